// Round 9
// baseline (602.039 us; speedup 1.0000x reference)
//
#include <hip/hip_runtime.h>
#include <hip/hip_bf16.h>
#include <stdint.h>
#include <stddef.h>

typedef __hip_bfloat16 bf16;
typedef __attribute__((ext_vector_type(8))) __bf16 bf16x8;
typedef __attribute__((ext_vector_type(4))) float f32x4;

__device__ __forceinline__ bf16 f2b(float x) { return __float2bfloat16(x); }

// async global->LDS copy, 16B per lane. LDS dest must be wave-uniform base + lane*16.
__device__ __forceinline__ void async_copy16(const bf16* g, bf16* l) {
    __builtin_amdgcn_global_load_lds(
        (const __attribute__((address_space(1))) unsigned int*)g,
        (__attribute__((address_space(3))) unsigned int*)l,
        16, 0, 0);
}

// XCD-aware remap: blocks dispatch round-robin to 8 XCDs by l%8. Map each group of
// 64 consecutive l to 8 m-tiles x 8 n-tiles so the 8 blocks of one XCD share ONE
// m-tile -> A row-tile fetched once into that XCD's L2. (r8: FETCH 1.05GB -> 128MB)
__device__ __forceinline__ void remap_xcd(int l, int mt, int& mtile, int& ntile) {
    int g  = l >> 6;
    int r  = l & 63;
    int gm = g << 3;
    if (gm + 8 <= mt) { mtile = gm + (r & 7); ntile = r >> 3; }
    else { int p = mt - gm; mtile = gm + (r % p); ntile = r / p; }  // tail group
}

// ---------------------------------------------------------------- utility kernels
__global__ void zero_kernel(float* __restrict__ p, int n) {
    int i = blockIdx.x * blockDim.x + threadIdx.x;
    if (i < n) p[i] = 0.f;
}

// W1T[n*320 + p]: padded-triplet layout. p = t*32 + q; q<30 -> W1[(t*30+q)*1024 + n], else 0.
__global__ void transpose_w1_pad32(const float* __restrict__ W1, bf16* __restrict__ WT) {
    int idx = blockIdx.x * blockDim.x + threadIdx.x;
    if (idx >= 1024 * 320) return;
    int n = idx / 320;
    int p = idx - n * 320;
    int t = p >> 5;
    int q = p & 31;
    float v = (q < 30) ? W1[(size_t)(t * 30 + q) * 1024 + n] : 0.f;
    WT[idx] = f2b(v);
}

// Tiled transpose+cast for W2: WT[n*Kpad+k] = bf16(W[k*N+n]). 64x64 tiles via LDS.
__global__ __launch_bounds__(256)
void transpose_pad_tiled(const float* __restrict__ W, bf16* __restrict__ WT,
                         int K, int N, int Kpad) {
    __shared__ bf16 tile[64][65];
    const int t = threadIdx.x;
    const int tk = blockIdx.x * 64;
    const int tn = blockIdx.y * 64;
    #pragma unroll
    for (int r = 0; r < 16; ++r) {
        int kl = (t >> 6) + r * 4;
        int nl = t & 63;
        int k = tk + kl, n = tn + nl;
        float v = (k < K) ? W[(size_t)k * N + n] : 0.f;
        tile[kl][nl] = f2b(v);
    }
    __syncthreads();
    #pragma unroll
    for (int r = 0; r < 16; ++r) {
        int nl = (t >> 6) + r * 4;
        int kl = t & 63;
        WT[(size_t)(tn + nl) * Kpad + tk + kl] = tile[kl][nl];
    }
}

// ---------------------------------------------------------------- fused feat + GEMM1
// Block owns 64 rows. Phase 0: features computed ONCE into LDS sF[64][320] (swizzled
// 16B chunks: chunk c of row r at (c&~7)|((c&7)^(r&7)) -- same phase math as the
// verified conflict-free 64-elem-row layout, since 640B row stride == 0 mod 128B).
// Then serial loop over 8 n-tiles: stage only W1T slices (L2-resident), MFMA with
// A resident in sF. Epilogue: bias+relu -> padded LDS tile (row stride 132 elems ->
// banks shift by 2 per row) -> 256B-contiguous X1 row-segment stores.
// Waves: 2x2 over (64 rows x 128 cols); wave-tile 32x64 = acc[2][4] of 16x16 frags.
__global__ __launch_bounds__(256)
void gemm1_fused(const float* __restrict__ S, const float* __restrict__ E,
                 const bf16* __restrict__ BT, const float* __restrict__ bias,
                 bf16* __restrict__ X1) {
    __shared__ bf16 sF[64 * 320];
    __shared__ bf16 sB[128 * 64];
    __shared__ bf16 sOut[64 * 132];
    const int tid = threadIdx.x;
    const size_t m0 = (size_t)blockIdx.x * 64;

    // ---- phase 0: features (each thread: 2-3 triplets of one row)
    {
        int row = tid >> 2;
        int tp  = tid & 3;
        for (int t = tp; t < 10; t += 4) {
            const float* sp = S + (m0 + row) * 30 + t * 3;
            float fi = sp[0], fj = sp[1], d = sp[2];
            int ii = (int)fi;
            int jj = (int)fj;
            bf16 f[32];
            #pragma unroll
            for (int q = 0; q < 10; ++q) f[q]      = f2b((ii != 0) ? E[ii * 10 + q] : 0.f);
            #pragma unroll
            for (int q = 0; q < 10; ++q) f[10 + q] = f2b((jj != 0) ? E[jj * 10 + q] : 0.f);
            #pragma unroll
            for (int q = 0; q < 10; ++q) {
                float df = (float)(q + 1) * 0.7f - d;
                f[20 + q] = f2b((ii != 0) ? __expf(-df * df) : 0.f);   // GAMMA = 1
            }
            f[30] = f2b(0.f);
            f[31] = f2b(0.f);
            #pragma unroll
            for (int j = 0; j < 4; ++j) {
                int c0 = t * 4 + j;                       // logical chunk 0..39
                int p  = (c0 & ~7) | ((c0 & 7) ^ (row & 7));
                *(bf16x8*)&sF[row * 320 + p * 8] = *(const bf16x8*)&f[j * 8];
            }
        }
    }
    const int lane = tid & 63, wave = tid >> 6;
    const int wr = wave >> 1, wc = wave & 1;
    const int l16 = lane & 15, quad = lane >> 4;
    __syncthreads();

    for (int n = 0; n < 8; ++n) {
        const int n0 = n * 128;
        f32x4 acc[2][4];
        #pragma unroll
        for (int i = 0; i < 2; ++i)
            #pragma unroll
            for (int j = 0; j < 4; ++j) acc[i][j] = (f32x4){0.f, 0.f, 0.f, 0.f};

        for (int kk = 0; kk < 5; ++kk) {
            #pragma unroll
            for (int i = 0; i < 4; ++i) {
                int s   = i * 256 + tid;          // 0..1023
                int row = s >> 3;                 // 0..127 (W1T row = output col)
                int kof = ((s & 7) ^ (row & 7)) << 3;
                async_copy16(BT + (size_t)(n0 + row) * 320 + kk * 64 + kof, &sB[s * 8]);
            }
            __syncthreads();
            #pragma unroll
            for (int s2 = 0; s2 < 2; ++s2) {
                int cB = s2 * 4 + quad;                   // chunk within BK
                int cA = kk * 8 + s2 * 4 + quad;          // global A chunk 0..39
                bf16x8 a[2], b[4];
                #pragma unroll
                for (int mi = 0; mi < 2; ++mi) {
                    int r = wr * 32 + mi * 16 + l16;
                    int p = (cA & ~7) | ((cA & 7) ^ (r & 7));
                    a[mi] = *(const bf16x8*)&sF[r * 320 + p * 8];
                }
                #pragma unroll
                for (int ni = 0; ni < 4; ++ni) {
                    int r = wc * 64 + ni * 16 + l16;
                    b[ni] = *(const bf16x8*)&sB[r * 64 + ((cB ^ (r & 7)) << 3)];
                }
                #pragma unroll
                for (int mi = 0; mi < 2; ++mi)
                    #pragma unroll
                    for (int ni = 0; ni < 4; ++ni)
                        acc[mi][ni] = __builtin_amdgcn_mfma_f32_16x16x32_bf16(
                            a[mi], b[ni], acc[mi][ni], 0, 0, 0);
            }
            __syncthreads();
        }

        // epilogue: bias + relu -> sOut (padded), then coalesced row stores
        #pragma unroll
        for (int mi = 0; mi < 2; ++mi) {
            #pragma unroll
            for (int ni = 0; ni < 4; ++ni) {
                int col = wc * 64 + ni * 16 + l16;        // 0..127 local
                float bv = bias[n0 + col];
                #pragma unroll
                for (int r = 0; r < 4; ++r) {
                    int row = wr * 32 + mi * 16 + quad * 4 + r;   // 0..63
                    float v = acc[mi][ni][r] + bv;
                    v = v > 0.f ? v : 0.f;
                    sOut[row * 132 + col] = f2b(v);
                }
            }
        }
        __syncthreads();
        #pragma unroll
        for (int ps = 0; ps < 4; ++ps) {
            int r  = (tid >> 4) + ps * 16;                // 0..63
            int ch = tid & 15;                            // 16 chunks = 128 cols
            *(bf16x8*)(X1 + (m0 + r) * 1024 + n0 + ch * 8) =
                *(const bf16x8*)&sOut[r * 132 + ch * 8];
        }
        __syncthreads();
    }
}

// ---------------------------------------------------------------- GEMM2 (r8 winner, unchanged)
// outf[row] += sum_col relu(X1 @ W2T^T + b2)[col] * w3[col];  XOR-swizzled LDS,
// global_load_lds staging, XCD remap, atomicAdd fp32.
__global__ __launch_bounds__(256)
void gemm2_kernel(const bf16* __restrict__ A, const bf16* __restrict__ BT,
                  const float* __restrict__ bias, float* __restrict__ outf,
                  const float* __restrict__ w3, int K, int lda, int ldbt, int mt) {
    __shared__ bf16 sA[128 * 64];
    __shared__ bf16 sB[128 * 64];
    const int tid  = threadIdx.x;
    const int lane = tid & 63;
    const int wave = tid >> 6;
    const int wr = wave >> 1, wc = wave & 1;
    const int l16 = lane & 15, quad = lane >> 4;
    int mtile, ntile;
    remap_xcd(blockIdx.x, mt, mtile, ntile);
    const size_t m0 = (size_t)mtile * 128;
    const int    n0 = ntile * 128;

    f32x4 acc[4][4];
    #pragma unroll
    for (int i = 0; i < 4; ++i)
        #pragma unroll
        for (int j = 0; j < 4; ++j) acc[i][j] = (f32x4){0.f, 0.f, 0.f, 0.f};

    for (int kk = 0; kk < K; kk += 64) {
        #pragma unroll
        for (int i = 0; i < 4; ++i) {
            int s   = i * 256 + tid;
            int row = s >> 3;
            int kof = (((s & 7) ^ (row & 7)) << 3);
            async_copy16(A  + (m0 + row) * lda          + kk + kof, &sA[s * 8]);
            async_copy16(BT + (size_t)(n0 + row) * ldbt + kk + kof, &sB[s * 8]);
        }
        __syncthreads();
        #pragma unroll
        for (int s2 = 0; s2 < 2; ++s2) {
            int clog = s2 * 4 + quad;
            bf16x8 a[4], b[4];
            #pragma unroll
            for (int mi = 0; mi < 4; ++mi) {
                int r = wr * 64 + mi * 16 + l16;
                a[mi] = *(const bf16x8*)&sA[r * 64 + ((clog ^ (r & 7)) << 3)];
            }
            #pragma unroll
            for (int ni = 0; ni < 4; ++ni) {
                int r = wc * 64 + ni * 16 + l16;
                b[ni] = *(const bf16x8*)&sB[r * 64 + ((clog ^ (r & 7)) << 3)];
            }
            #pragma unroll
            for (int mi = 0; mi < 4; ++mi)
                #pragma unroll
                for (int ni = 0; ni < 4; ++ni)
                    acc[mi][ni] = __builtin_amdgcn_mfma_f32_16x16x32_bf16(
                        a[mi], b[ni], acc[mi][ni], 0, 0, 0);
        }
        __syncthreads();
    }

    #pragma unroll
    for (int mi = 0; mi < 4; ++mi) {
        #pragma unroll
        for (int r = 0; r < 4; ++r) {
            float p = 0.f;
            #pragma unroll
            for (int ni = 0; ni < 4; ++ni) {
                int col = n0 + wc * 64 + ni * 16 + l16;
                float v = acc[mi][ni][r] + bias[col];
                v = v > 0.f ? v : 0.f;
                p += v * w3[col];
            }
            #pragma unroll
            for (int off = 1; off < 16; off <<= 1)
                p += __shfl_xor(p, off, 64);
            if (l16 == 0) {
                size_t row = m0 + wr * 64 + mi * 16 + quad * 4 + r;
                atomicAdd(&outf[row], p);
            }
        }
    }
}

__global__ void final_kernel(const float* __restrict__ outf, const float* __restrict__ b3,
                             float* __restrict__ out, int n) {
    int i = blockIdx.x * blockDim.x + threadIdx.x;
    if (i < n) out[i] = outf[i] + b3[0];
}

// ---------------------------------------------------------------- zero-workspace fallback
#define FB_ROWS 8
__global__ __launch_bounds__(256)
void fallback_kernel(const float* __restrict__ S, const float* __restrict__ E,
                     const float* __restrict__ W1, const float* __restrict__ b1,
                     const float* __restrict__ W2, const float* __restrict__ b2,
                     const float* __restrict__ W3, const float* __restrict__ b3,
                     float* __restrict__ out) {
    __shared__ float feat[FB_ROWS][304];
    __shared__ float X1[FB_ROWS][1024];
    __shared__ float red[256];
    const int tid = threadIdx.x;
    const size_t r0 = (size_t)blockIdx.x * FB_ROWS;

    if (tid < FB_ROWS * 10) {
        int r = tid / 10, t = tid - r * 10;
        const float* s = S + (r0 + r) * 30 + t * 3;
        float fi = s[0], fj = s[1], d = s[2];
        int ii = (int)fi;
        int jj = (int)fj;
        float* o = &feat[r][t * 30];
        #pragma unroll
        for (int c = 0; c < 10; ++c) o[c]      = (ii != 0) ? E[ii * 10 + c] : 0.f;
        #pragma unroll
        for (int c = 0; c < 10; ++c) o[10 + c] = (jj != 0) ? E[jj * 10 + c] : 0.f;
        #pragma unroll
        for (int c = 0; c < 10; ++c) {
            float df = (float)(c + 1) * 0.7f - d;
            o[20 + c] = (ii != 0) ? __expf(-df * df) : 0.f;
        }
    }
    __syncthreads();

    for (int i = 0; i < FB_ROWS * 1024 / 256; ++i) {
        int idx = i * 256 + tid;
        int r = idx & (FB_ROWS - 1);
        int c = idx >> 3;
        float a = b1[c];
        for (int k = 0; k < 300; ++k)
            a += feat[r][k] * W1[(size_t)k * 1024 + c];
        X1[r][c] = a > 0.f ? a : 0.f;
    }
    __syncthreads();

    {
        int r  = tid & (FB_ROWS - 1);
        int cg = tid >> 3;
        float acc = 0.f;
        for (int cc = 0; cc < 32; ++cc) {
            int c = cg * 32 + cc;
            float a = b2[c];
            for (int k = 0; k < 1024; ++k)
                a += X1[r][k] * W2[(size_t)k * 1024 + c];
            a = a > 0.f ? a : 0.f;
            acc += a * W3[c];
        }
        red[tid] = acc;
    }
    __syncthreads();
    if (tid < FB_ROWS) {
        float s = 0.f;
        for (int g = 0; g < 32; ++g) s += red[g * FB_ROWS + tid];
        out[r0 + tid] = s + b3[0];
    }
}

// ---------------------------------------------------------------- launch
extern "C" void kernel_launch(void* const* d_in, const int* in_sizes, int n_in,
                              void* d_out, int out_size, void* d_ws, size_t ws_size,
                              hipStream_t stream) {
    const float* S  = (const float*)d_in[0];
    const float* E  = (const float*)d_in[1];
    const float* W1 = (const float*)d_in[2];
    const float* b1 = (const float*)d_in[3];
    const float* W2 = (const float*)d_in[4];
    const float* b2 = (const float*)d_in[5];
    const float* W3 = (const float*)d_in[6];
    const float* b3 = (const float*)d_in[7];
    float* out = (float*)d_out;

    const int Bn  = out_size;   // 131072
    const int HID = 1024;
    const int K1  = 320;

    const size_t MIN_WS = 16u * 1024u * 1024u;
    if (ws_size < MIN_WS) {
        fallback_kernel<<<Bn / FB_ROWS, 256, 0, stream>>>(S, E, W1, b1, W2, b2, W3, b3, out);
        return;
    }

    char* ws = (char*)d_ws;
    size_t off = 0;
    auto take = [&](size_t bytes) { char* p = ws + off; off += (bytes + 255) & ~(size_t)255; return p; };
    float* outf = (float*)take((size_t)Bn * sizeof(float));
    bf16*  W1T  = (bf16*) take((size_t)HID * K1 * sizeof(bf16));
    bf16*  W2T  = (bf16*) take((size_t)HID * HID * sizeof(bf16));

    size_t avail   = ws_size - off - 256;
    size_t per_row = (size_t)HID * sizeof(bf16);          // X1 only (feat fused away)
    size_t chunk   = (avail / per_row) & ~(size_t)1023;   // multiple of 1024 rows
    if (chunk > (size_t)Bn) chunk = Bn;
    bf16* X1c = (bf16*)take(chunk * HID * sizeof(bf16));

    zero_kernel<<<(Bn + 255) / 256, 256, 0, stream>>>(outf, Bn);
    transpose_w1_pad32<<<(HID * K1 + 255) / 256, 256, 0, stream>>>(W1, W1T);
    {
        dim3 g2(HID / 64, HID / 64);
        transpose_pad_tiled<<<g2, 256, 0, stream>>>(W2, W2T, HID, HID, HID);
    }

    for (size_t r0 = 0; r0 < (size_t)Bn; r0 += chunk) {
        size_t rows = ((size_t)Bn - r0 < chunk) ? ((size_t)Bn - r0) : chunk;
        int mt = (int)(rows / 128);
        gemm1_fused<<<(unsigned)(rows / 64), 256, 0, stream>>>(S + r0 * 30, E, W1T, b1, X1c);
        gemm2_kernel<<<(unsigned)(mt * 8), 256, 0, stream>>>(
            X1c, W2T, b2, outf + r0, W3, HID, HID, HID, mt);
    }
    final_kernel<<<(Bn + 255) / 256, 256, 0, stream>>>(outf, b3, out, Bn);
}

// Round 10
// 518.439 us; speedup vs baseline: 1.1613x; 1.1613x over previous
//
#include <hip/hip_runtime.h>
#include <hip/hip_bf16.h>
#include <stdint.h>
#include <stddef.h>

typedef __hip_bfloat16 bf16;
typedef __attribute__((ext_vector_type(8))) __bf16 bf16x8;
typedef __attribute__((ext_vector_type(4))) float f32x4;

__device__ __forceinline__ bf16 f2b(float x) { return __float2bfloat16(x); }

// async global->LDS copy, 16B per lane. LDS dest must be wave-uniform base + lane*16.
__device__ __forceinline__ void async_copy16(const bf16* g, bf16* l) {
    __builtin_amdgcn_global_load_lds(
        (const __attribute__((address_space(1))) unsigned int*)g,
        (__attribute__((address_space(3))) unsigned int*)l,
        16, 0, 0);
}

// XCD-aware remap: blocks dispatch round-robin to 8 XCDs by l%8. Map each group of
// 64 consecutive l to 8 m-tiles x 8 n-tiles so the 8 blocks of one XCD share ONE
// m-tile -> A row-tile fetched once into that XCD's L2. (r8: FETCH 1.05GB -> 128MB)
__device__ __forceinline__ void remap_xcd(int l, int mt, int& mtile, int& ntile) {
    int g  = l >> 6;
    int r  = l & 63;
    int gm = g << 3;
    if (gm + 8 <= mt) { mtile = gm + (r & 7); ntile = r >> 3; }
    else { int p = mt - gm; mtile = gm + (r % p); ntile = r / p; }  // tail group
}

// ---------------------------------------------------------------- utility kernels
__global__ void zero_kernel(float* __restrict__ p, int n) {
    int i = blockIdx.x * blockDim.x + threadIdx.x;
    if (i < n) p[i] = 0.f;
}

// W1T[n*320 + p]: padded-triplet layout. p = t*32 + q; q<30 -> W1[(t*30+q)*1024 + n], else 0.
__global__ void transpose_w1_pad32(const float* __restrict__ W1, bf16* __restrict__ WT) {
    int idx = blockIdx.x * blockDim.x + threadIdx.x;
    if (idx >= 1024 * 320) return;
    int n = idx / 320;
    int p = idx - n * 320;
    int t = p >> 5;
    int q = p & 31;
    float v = (q < 30) ? W1[(size_t)(t * 30 + q) * 1024 + n] : 0.f;
    WT[idx] = f2b(v);
}

// Tiled transpose+cast for W2: WT[n*Kpad+k] = bf16(W[k*N+n]). 64x64 tiles via LDS.
__global__ __launch_bounds__(256)
void transpose_pad_tiled(const float* __restrict__ W, bf16* __restrict__ WT,
                         int K, int N, int Kpad) {
    __shared__ bf16 tile[64][65];
    const int t = threadIdx.x;
    const int tk = blockIdx.x * 64;
    const int tn = blockIdx.y * 64;
    #pragma unroll
    for (int r = 0; r < 16; ++r) {
        int kl = (t >> 6) + r * 4;
        int nl = t & 63;
        int k = tk + kl, n = tn + nl;
        float v = (k < K) ? W[(size_t)k * N + n] : 0.f;
        tile[kl][nl] = f2b(v);
    }
    __syncthreads();
    #pragma unroll
    for (int r = 0; r < 16; ++r) {
        int nl = (t >> 6) + r * 4;
        int kl = t & 63;
        WT[(size_t)(tn + nl) * Kpad + tk + kl] = tile[kl][nl];
    }
}

// ---------------------------------------------------------------- feature kernel (r8 winner)
// 128 rows/block; features computed once, staged in LDS (XOR-swizzled chunks),
// stored fully coalesced bf16x8. feat layout: row*320 + t*32 + q.
__global__ __launch_bounds__(256)
void feat_kernel(const float* __restrict__ S, const float* __restrict__ E,
                 bf16* __restrict__ feat) {
    __shared__ bf16 sF[128 * 320];
    const int tid = threadIdx.x;
    const size_t r0 = (size_t)blockIdx.x * 128;
    const int row = tid >> 1, tp = tid & 1;

    #pragma unroll
    for (int c = 0; c < 5; ++c) {
        int t = c * 2 + tp;
        const float* sp = S + (r0 + row) * 30 + t * 3;
        float fi = sp[0], fj = sp[1], d = sp[2];
        int ii = (int)fi;
        int jj = (int)fj;
        bf16 f[32];
        #pragma unroll
        for (int q = 0; q < 10; ++q) f[q]      = f2b((ii != 0) ? E[ii * 10 + q] : 0.f);
        #pragma unroll
        for (int q = 0; q < 10; ++q) f[10 + q] = f2b((jj != 0) ? E[jj * 10 + q] : 0.f);
        #pragma unroll
        for (int q = 0; q < 10; ++q) {
            float df = (float)(q + 1) * 0.7f - d;
            f[20 + q] = f2b((ii != 0) ? __expf(-df * df) : 0.f);   // GAMMA = 1
        }
        f[30] = f2b(0.f);
        f[31] = f2b(0.f);
        #pragma unroll
        for (int j = 0; j < 4; ++j) {
            int c0 = t * 4 + j;
            *(bf16x8*)&sF[row * 320 + ((c0 ^ (row & 7)) << 3)] = *(const bf16x8*)&f[j * 8];
        }
    }
    __syncthreads();
    #pragma unroll
    for (int i = 0; i < 20; ++i) {
        int c2 = i * 256 + tid;        // 0..5119
        int r  = c2 / 40;
        int c  = c2 - r * 40;
        int p  = c ^ (r & 7);
        *(bf16x8*)(feat + r0 * 320 + (size_t)c2 * 8) = *(const bf16x8*)&sF[r * 320 + p * 8];
    }
}

// ---------------------------------------------------------------- MFMA GEMM (XOR-swizzled LDS)
// C[M,N] = A[M,K] @ BT[N,K]^T ; 128x128 tile, BK=64, 4 waves (2x2), 4x4 16x16x32 frags.
// KTOTAL is compile-time -> K-loop fully unrolled: global_load_lds gets base+imm
// addresses (13-bit imm, max 1920B), LDS offsets become literals -> kills the
// per-iter v_lshl_add_u64 address chains (m98: ~21/iter) behind VALUBusy 53%.
// 1-D grid (mt*8 blocks) with XCD-aware remap.
// EPI==0: C = relu(acc + bias) stored bf16.   EPI==1: outf[row] += relu-dot-w3.
template <int EPI, int KTOTAL>
__global__ __launch_bounds__(256)
void gemm_kernel(const bf16* __restrict__ A, const bf16* __restrict__ BT,
                 const float* __restrict__ bias, bf16* __restrict__ C,
                 float* __restrict__ outf, const float* __restrict__ w3,
                 int lda, int ldbt, int ldc, int mt) {
    __shared__ bf16 sA[128 * 64];
    __shared__ bf16 sB[128 * 64];
    const int tid  = threadIdx.x;
    const int lane = tid & 63;
    const int wave = tid >> 6;
    const int wr = wave >> 1, wc = wave & 1;
    const int l16 = lane & 15, quad = lane >> 4;
    int mtile, ntile;
    remap_xcd(blockIdx.x, mt, mtile, ntile);
    const size_t m0 = (size_t)mtile * 128;
    const int    n0 = ntile * 128;

    // loop-invariant staging bases (kk enters as an immediate offset after unroll)
    const bf16* gA[4];
    const bf16* gB[4];
    #pragma unroll
    for (int i = 0; i < 4; ++i) {
        int s   = i * 256 + tid;
        int row = s >> 3;
        int kof = (((s & 7) ^ (row & 7)) << 3);
        gA[i] = A  + (m0 + row) * lda          + kof;
        gB[i] = BT + (size_t)(n0 + row) * ldbt + kof;
    }

    f32x4 acc[4][4];
    #pragma unroll
    for (int i = 0; i < 4; ++i)
        #pragma unroll
        for (int j = 0; j < 4; ++j) acc[i][j] = (f32x4){0.f, 0.f, 0.f, 0.f};

    #pragma unroll
    for (int kk = 0; kk < KTOTAL; kk += 64) {
        #pragma unroll
        for (int i = 0; i < 4; ++i) {
            int s = i * 256 + tid;
            async_copy16(gA[i] + kk, &sA[s * 8]);
            async_copy16(gB[i] + kk, &sB[s * 8]);
        }
        __syncthreads();
        #pragma unroll
        for (int s2 = 0; s2 < 2; ++s2) {
            int clog = s2 * 4 + quad;
            bf16x8 a[4], b[4];
            #pragma unroll
            for (int mi = 0; mi < 4; ++mi) {
                int r = wr * 64 + mi * 16 + l16;
                a[mi] = *(const bf16x8*)&sA[r * 64 + ((clog ^ (r & 7)) << 3)];
            }
            #pragma unroll
            for (int ni = 0; ni < 4; ++ni) {
                int r = wc * 64 + ni * 16 + l16;
                b[ni] = *(const bf16x8*)&sB[r * 64 + ((clog ^ (r & 7)) << 3)];
            }
            #pragma unroll
            for (int mi = 0; mi < 4; ++mi)
                #pragma unroll
                for (int ni = 0; ni < 4; ++ni)
                    acc[mi][ni] = __builtin_amdgcn_mfma_f32_16x16x32_bf16(
                        a[mi], b[ni], acc[mi][ni], 0, 0, 0);
        }
        __syncthreads();
    }

    if (EPI == 0) {
        #pragma unroll
        for (int mi = 0; mi < 4; ++mi) {
            #pragma unroll
            for (int ni = 0; ni < 4; ++ni) {
                int col = n0 + wc * 64 + ni * 16 + l16;
                float bv = bias[col];
                #pragma unroll
                for (int r = 0; r < 4; ++r) {
                    size_t row = m0 + wr * 64 + mi * 16 + quad * 4 + r;
                    float v = acc[mi][ni][r] + bv;
                    v = v > 0.f ? v : 0.f;
                    C[row * ldc + col] = f2b(v);
                }
            }
        }
    } else {
        #pragma unroll
        for (int mi = 0; mi < 4; ++mi) {
            #pragma unroll
            for (int r = 0; r < 4; ++r) {
                float p = 0.f;
                #pragma unroll
                for (int ni = 0; ni < 4; ++ni) {
                    int col = n0 + wc * 64 + ni * 16 + l16;
                    float v = acc[mi][ni][r] + bias[col];
                    v = v > 0.f ? v : 0.f;
                    p += v * w3[col];
                }
                #pragma unroll
                for (int off = 1; off < 16; off <<= 1)
                    p += __shfl_xor(p, off, 64);
                if (l16 == 0) {
                    size_t row = m0 + wr * 64 + mi * 16 + quad * 4 + r;
                    atomicAdd(&outf[row], p);
                }
            }
        }
    }
}

__global__ void final_kernel(const float* __restrict__ outf, const float* __restrict__ b3,
                             float* __restrict__ out, int n) {
    int i = blockIdx.x * blockDim.x + threadIdx.x;
    if (i < n) out[i] = outf[i] + b3[0];
}

// ---------------------------------------------------------------- zero-workspace fallback
#define FB_ROWS 8
__global__ __launch_bounds__(256)
void fallback_kernel(const float* __restrict__ S, const float* __restrict__ E,
                     const float* __restrict__ W1, const float* __restrict__ b1,
                     const float* __restrict__ W2, const float* __restrict__ b2,
                     const float* __restrict__ W3, const float* __restrict__ b3,
                     float* __restrict__ out) {
    __shared__ float feat[FB_ROWS][304];
    __shared__ float X1[FB_ROWS][1024];
    __shared__ float red[256];
    const int tid = threadIdx.x;
    const size_t r0 = (size_t)blockIdx.x * FB_ROWS;

    if (tid < FB_ROWS * 10) {
        int r = tid / 10, t = tid - r * 10;
        const float* s = S + (r0 + r) * 30 + t * 3;
        float fi = s[0], fj = s[1], d = s[2];
        int ii = (int)fi;
        int jj = (int)fj;
        float* o = &feat[r][t * 30];
        #pragma unroll
        for (int c = 0; c < 10; ++c) o[c]      = (ii != 0) ? E[ii * 10 + c] : 0.f;
        #pragma unroll
        for (int c = 0; c < 10; ++c) o[10 + c] = (jj != 0) ? E[jj * 10 + c] : 0.f;
        #pragma unroll
        for (int c = 0; c < 10; ++c) {
            float df = (float)(c + 1) * 0.7f - d;
            o[20 + c] = (ii != 0) ? __expf(-df * df) : 0.f;
        }
    }
    __syncthreads();

    for (int i = 0; i < FB_ROWS * 1024 / 256; ++i) {
        int idx = i * 256 + tid;
        int r = idx & (FB_ROWS - 1);
        int c = idx >> 3;
        float a = b1[c];
        for (int k = 0; k < 300; ++k)
            a += feat[r][k] * W1[(size_t)k * 1024 + c];
        X1[r][c] = a > 0.f ? a : 0.f;
    }
    __syncthreads();

    {
        int r  = tid & (FB_ROWS - 1);
        int cg = tid >> 3;
        float acc = 0.f;
        for (int cc = 0; cc < 32; ++cc) {
            int c = cg * 32 + cc;
            float a = b2[c];
            for (int k = 0; k < 1024; ++k)
                a += X1[r][k] * W2[(size_t)k * 1024 + c];
            a = a > 0.f ? a : 0.f;
            acc += a * W3[c];
        }
        red[tid] = acc;
    }
    __syncthreads();
    if (tid < FB_ROWS) {
        float s = 0.f;
        for (int g = 0; g < 32; ++g) s += red[g * FB_ROWS + tid];
        out[r0 + tid] = s + b3[0];
    }
}

// ---------------------------------------------------------------- launch
extern "C" void kernel_launch(void* const* d_in, const int* in_sizes, int n_in,
                              void* d_out, int out_size, void* d_ws, size_t ws_size,
                              hipStream_t stream) {
    const float* S  = (const float*)d_in[0];
    const float* E  = (const float*)d_in[1];
    const float* W1 = (const float*)d_in[2];
    const float* b1 = (const float*)d_in[3];
    const float* W2 = (const float*)d_in[4];
    const float* b2 = (const float*)d_in[5];
    const float* W3 = (const float*)d_in[6];
    const float* b3 = (const float*)d_in[7];
    float* out = (float*)d_out;

    const int Bn  = out_size;   // 131072
    const int HID = 1024;
    const int K1  = 320;

    const size_t MIN_WS = 16u * 1024u * 1024u;
    if (ws_size < MIN_WS) {
        fallback_kernel<<<Bn / FB_ROWS, 256, 0, stream>>>(S, E, W1, b1, W2, b2, W3, b3, out);
        return;
    }

    char* ws = (char*)d_ws;
    size_t off = 0;
    auto take = [&](size_t bytes) { char* p = ws + off; off += (bytes + 255) & ~(size_t)255; return p; };
    float* outf = (float*)take((size_t)Bn * sizeof(float));
    bf16*  W1T  = (bf16*) take((size_t)HID * K1 * sizeof(bf16));
    bf16*  W2T  = (bf16*) take((size_t)HID * HID * sizeof(bf16));

    size_t avail   = ws_size - off - 256;
    size_t per_row = (size_t)K1 * sizeof(bf16) + (size_t)HID * sizeof(bf16); // 2688 B (r8 match)
    size_t chunk   = (avail / per_row) & ~(size_t)1023;   // multiple of 1024 rows
    if (chunk > (size_t)Bn) chunk = Bn;
    bf16* featc = (bf16*)take(chunk * K1 * sizeof(bf16));
    bf16* X1c   = (bf16*)take(chunk * HID * sizeof(bf16));

    zero_kernel<<<(Bn + 255) / 256, 256, 0, stream>>>(outf, Bn);
    transpose_w1_pad32<<<(HID * K1 + 255) / 256, 256, 0, stream>>>(W1, W1T);
    {
        dim3 g2(HID / 64, HID / 64);
        transpose_pad_tiled<<<g2, 256, 0, stream>>>(W2, W2T, HID, HID, HID);
    }

    for (size_t r0 = 0; r0 < (size_t)Bn; r0 += chunk) {
        size_t rows = ((size_t)Bn - r0 < chunk) ? ((size_t)Bn - r0) : chunk;
        int mt = (int)(rows / 128);
        feat_kernel<<<(unsigned)(rows / 128), 256, 0, stream>>>(S + r0 * 30, E, featc);
        gemm_kernel<0, 320><<<(unsigned)(mt * 8), 256, 0, stream>>>(
            featc, W1T, b1, X1c, nullptr, nullptr, K1, K1, HID, mt);
        gemm_kernel<1, 1024><<<(unsigned)(mt * 8), 256, 0, stream>>>(
            X1c, W2T, b2, nullptr, outf + r0, W3, HID, HID, 0, mt);
    }
    final_kernel<<<(Bn + 255) / 256, 256, 0, stream>>>(outf, b3, out, Bn);
}